// Round 4
// baseline (1135.083 us; speedup 1.0000x reference)
//
#include <hip/hip_runtime.h>
#include <hip/hip_bf16.h>

typedef __attribute__((ext_vector_type(8))) short bf16x8;
typedef __attribute__((ext_vector_type(16))) float f32x16;
typedef __attribute__((ext_vector_type(4))) unsigned int uint4v;
typedef unsigned short ushort_t;
typedef unsigned int uint_t;

#define N_NODES 16384
#define HD 128
#define NOUT 384
#define BT_K 16640            // 16384 + 128 + 128
#define LSTR 72               // LDS row stride in shorts (36 dwords = 4 mod 32: conflict-free)

static __device__ __forceinline__ ushort_t f2bf(float f) {
  __hip_bfloat16 b = __float2bfloat16(f);
  return *reinterpret_cast<ushort_t*>(&b);
}

// ---------------- fused prep ----------------
// blocks [0,1536): A (16384x384 f32) -> Bt (384x16640 bf16) transpose
// blocks [1536,1728): U1,U2 -> Bt tail columns
// blocks [1728,2240): neighbour_h -> h1bf, h2bf (m-major), h1t (i-major)
__global__ void prep_all(const float* __restrict__ A, const float* __restrict__ U1,
                         const float* __restrict__ U2, const float* __restrict__ nh,
                         ushort_t* __restrict__ Bt, ushort_t* __restrict__ h1,
                         ushort_t* __restrict__ h2, ushort_t* __restrict__ h1t) {
  __shared__ float sm[64][65];
  const int b = blockIdx.x;
  const int t = threadIdx.x;
  const int tx = t & 63, ty = t >> 6;
  if (b < 1536) {
    const int kt = b & 255, nt = b >> 8;
    const int k0 = kt * 64, n0 = nt * 64;
#pragma unroll
    for (int s = 0; s < 16; ++s) {
      int kk = ty + s * 4;
      sm[kk][tx] = A[(size_t)(k0 + kk) * NOUT + n0 + tx];
    }
    __syncthreads();
#pragma unroll
    for (int s = 0; s < 16; ++s) {
      int nn = ty + s * 4;
      Bt[(size_t)(n0 + nn) * BT_K + k0 + tx] = f2bf(sm[tx][nn]);
    }
  } else if (b < 1728) {
    int idx = (b - 1536) * 256 + t;   // 0..49151
    int n = idx >> 7, i = idx & 127;
    Bt[(size_t)n * BT_K + 16384 + i] = f2bf(U1[idx]);
    Bt[(size_t)n * BT_K + 16512 + i] = f2bf(U2[idx]);
  } else {
    const int g = b - 1728;           // 0..511
    const int mt = g & 255, jt = g >> 8;
    const int m0 = mt * 64, j0 = jt * 64;
#pragma unroll
    for (int s = 0; s < 16; ++s) {
      int mm = ty + s * 4;
      float f1 = nh[(size_t)(m0 + mm) * 256 + j0 + tx];
      float f2 = nh[(size_t)(m0 + mm) * 256 + 128 + j0 + tx];
      h1[(size_t)(m0 + mm) * HD + j0 + tx] = f2bf(f1);
      h2[(size_t)(m0 + mm) * HD + j0 + tx] = f2bf(f2);
      sm[mm][tx] = f1;
    }
    __syncthreads();
#pragma unroll
    for (int s = 0; s < 16; ++s) {
      int jj = ty + s * 4;
      h1t[(size_t)(j0 + jj) * N_NODES + m0 + tx] = f2bf(sm[tx][jj]);
    }
  }
}

// ---------------- main GEMM: out[m][n] = sum_k X[m,k] * Bt[n,k] (+bias) ----------------
// X[m, i*128+j] = h1[m,i]*h2[m,j] for i<128; X[m,16384+i]=h1[m,i]; X[m,16512+j]=h2[m,j]
// 260 K-tiles of 64: tiles 2*i,2*i+1 are the two halves of outer-product slice i;
// tiles 256..259 are the U1/U2 linear tails.
__global__ __launch_bounds__(256, 2)
void gemm_kernel(const ushort_t* __restrict__ Bt, const ushort_t* __restrict__ h1bf,
                 const ushort_t* __restrict__ h2bf, const ushort_t* __restrict__ h1t,
                 const float* __restrict__ u2b, float* __restrict__ out) {
  __shared__ short bsh[2][128 * LSTR];   // double-buffered B tile [n][k64]
  const int tid = threadIdx.x;
  const int bid = blockIdx.x;
  const int Nt = bid % 3, Mt = bid / 3;
  const int n0 = Nt * 128, m0 = Mt * 128;
  const int lane = tid & 63, wv = tid >> 6;
  const int l31 = lane & 31, oct = lane >> 5;
  const int wm = wv >> 1, wn = wv & 1;           // 2x2 wave grid
  const int mbase = m0 + wm * 64;
  const int nbase_l = wn * 64;

  // resident h2 A-fragments: rows mbase+ms*32+l31, k2 = c*16 + oct*8 + [0..8)
  uint4v h2u[2][8];
#pragma unroll
  for (int ms = 0; ms < 2; ++ms) {
    const ushort_t* hp = h2bf + (size_t)(mbase + ms * 32 + l31) * HD + oct * 8;
#pragma unroll
    for (int c = 0; c < 8; ++c)
      h2u[ms][c] = *reinterpret_cast<const uint4v*>(hp + c * 16);
  }

  f32x16 acc[2][2];
#pragma unroll
  for (int ms = 0; ms < 2; ++ms)
#pragma unroll
    for (int ns = 0; ns < 2; ++ns)
      acc[ms][ns] = (f32x16)(0.0f);

  // staging: 16 KB tile, 256 threads x 16 B; thread -> (row = tid>>3 + 32*l, col = (tid&7)*8)
  const int srow = tid >> 3;
  const int scol = (tid & 7) * 8;
  uint4 breg[4];
  auto load_breg = [&](int it) {
#pragma unroll
    for (int l = 0; l < 4; ++l)
      breg[l] = *reinterpret_cast<const uint4*>(
          Bt + (size_t)(n0 + srow + 32 * l) * BT_K + (size_t)it * 64 + scol);
  };
  auto write_breg = [&](int p) {
#pragma unroll
    for (int l = 0; l < 4; ++l)
      *reinterpret_cast<uint4*>(&bsh[p][(srow + 32 * l) * LSTR + scol]) = breg[l];
  };

  load_breg(0);
  write_breg(0);
  load_breg(1);

  // h1 scalar rolling prefetch (one per ms-row, advances every 2 tiles)
  const int hrow0 = mbase + l31;
  const int hrow1 = mbase + 32 + l31;
  ushort_t hn0 = h1t[hrow0];
  ushort_t hn1 = h1t[hrow1];
  float h1f0 = 0.0f, h1f1 = 0.0f;

  __syncthreads();

  int p = 0;
  for (int it = 0; it < 260; ++it) {
    if (it + 1 < 260) write_breg(p ^ 1);   // tile it+1 (loaded last iter; vmcnt wait hidden)
    if (it + 2 < 260) load_breg(it + 2);   // in flight across this tile's compute

    if (it < 256) {
      if ((it & 1) == 0) {
        h1f0 = __uint_as_float((uint_t)hn0 << 16);
        h1f1 = __uint_as_float((uint_t)hn1 << 16);
        int io = (it >> 1) + 1;
        if (io < 128) {
          hn0 = h1t[(size_t)io * N_NODES + hrow0];
          hn1 = h1t[(size_t)io * N_NODES + hrow1];
        }
      }
      const int half = (it & 1) * 4;
#pragma unroll
      for (int c = 0; c < 4; ++c) {
        bf16x8 b0 = *reinterpret_cast<const bf16x8*>(&bsh[p][(nbase_l + l31) * LSTR + c * 16 + oct * 8]);
        bf16x8 b1 = *reinterpret_cast<const bf16x8*>(&bsh[p][(nbase_l + 32 + l31) * LSTR + c * 16 + oct * 8]);
#pragma unroll
        for (int ms = 0; ms < 2; ++ms) {
          const float hf = ms ? h1f1 : h1f0;
          uint4v avu;
#pragma unroll
          for (int r = 0; r < 4; ++r) {
            uint_t u = h2u[ms][half + c][r];
            float lo = __uint_as_float(u << 16);
            float hi = __uint_as_float(u & 0xffff0000u);
            avu[r] = __builtin_amdgcn_perm(__float_as_uint(hi * hf), __float_as_uint(lo * hf),
                                           0x07060302u);
          }
          bf16x8 av = __builtin_bit_cast(bf16x8, avu);
          acc[ms][0] = __builtin_amdgcn_mfma_f32_32x32x16_bf16(av, b0, acc[ms][0], 0, 0, 0);
          acc[ms][1] = __builtin_amdgcn_mfma_f32_32x32x16_bf16(av, b1, acc[ms][1], 0, 0, 0);
        }
      }
    } else {
      const int tail = it - 256;   // 0,1: U1 halves; 2,3: U2 halves
#pragma unroll
      for (int c = 0; c < 4; ++c) {
        bf16x8 b0 = *reinterpret_cast<const bf16x8*>(&bsh[p][(nbase_l + l31) * LSTR + c * 16 + oct * 8]);
        bf16x8 b1 = *reinterpret_cast<const bf16x8*>(&bsh[p][(nbase_l + 32 + l31) * LSTR + c * 16 + oct * 8]);
#pragma unroll
        for (int ms = 0; ms < 2; ++ms) {
          bf16x8 a;
          if (tail < 2) {
            a = *reinterpret_cast<const bf16x8*>(
                &h1bf[(size_t)(mbase + ms * 32 + l31) * HD + tail * 64 + c * 16 + oct * 8]);
          } else {
            a = __builtin_bit_cast(bf16x8, h2u[ms][(tail - 2) * 4 + c]);
          }
          acc[ms][0] = __builtin_amdgcn_mfma_f32_32x32x16_bf16(a, b0, acc[ms][0], 0, 0, 0);
          acc[ms][1] = __builtin_amdgcn_mfma_f32_32x32x16_bf16(a, b1, acc[ms][1], 0, 0, 0);
        }
      }
    }
    __syncthreads();
    p ^= 1;
  }

  // epilogue: bias + store. C/D: col = lane&31, row = (reg&3) + 8*(reg>>2) + 4*oct
#pragma unroll
  for (int ns = 0; ns < 2; ++ns) {
    int col = n0 + nbase_l + ns * 32 + l31;
    float bias = u2b[col];
#pragma unroll
    for (int ms = 0; ms < 2; ++ms) {
#pragma unroll
      for (int r = 0; r < 16; ++r) {
        int row = (r & 3) + 8 * (r >> 2) + 4 * oct;
        int m = mbase + ms * 32 + row;
        out[(size_t)m * NOUT + col] = acc[ms][ns][r] + bias;
      }
    }
  }
}

extern "C" void kernel_launch(void* const* d_in, const int* in_sizes, int n_in,
                              void* d_out, int out_size, void* d_ws, size_t ws_size,
                              hipStream_t stream) {
  const float* nh  = (const float*)d_in[0];   // (16384, 2, 128)
  const float* A   = (const float*)d_in[1];   // (128, 128, 384)
  const float* U1  = (const float*)d_in[2];   // (384, 128)
  const float* U2  = (const float*)d_in[3];   // (384, 128)
  const float* U2b = (const float*)d_in[4];   // (384,)

  char* ws = (char*)d_ws;
  ushort_t* Bt   = (ushort_t*)(ws);                 // 384*16640*2  = 12,779,520
  ushort_t* h1bf = (ushort_t*)(ws + 12779520);      // 16384*128*2 =  4,194,304
  ushort_t* h2bf = (ushort_t*)(ws + 16973824);      //               4,194,304
  ushort_t* h1t  = (ushort_t*)(ws + 21168128);      //               4,194,304

  prep_all<<<dim3(2240), 256, 0, stream>>>(A, U1, U2, nh, Bt, h1bf, h2bf, h1t);
  gemm_kernel<<<dim3(384), 256, 0, stream>>>(Bt, h1bf, h2bf, h1t, U2b, (float*)d_out);
}

// Round 5
// 846.845 us; speedup vs baseline: 1.3404x; 1.3404x over previous
//
#include <hip/hip_runtime.h>
#include <hip/hip_bf16.h>

typedef __attribute__((ext_vector_type(8))) short bf16x8;
typedef __attribute__((ext_vector_type(16))) float f32x16;
typedef __attribute__((ext_vector_type(4))) unsigned int uint4v;
typedef unsigned short ushort_t;
typedef unsigned int uint_t;

#define N_NODES 16384
#define HD 128
#define NOUT 384
#define BT_K 16640            // 16384 + 128 + 128
#define LSTR 136              // LDS row stride in shorts (68 dwords = 4 mod 32: conflict-free, measured R1/R2)

static __device__ __forceinline__ ushort_t f2bf(float f) {
  __hip_bfloat16 b = __float2bfloat16(f);
  return *reinterpret_cast<ushort_t*>(&b);
}

// ---------------- fused prep ----------------
// blocks [0,1536): A (16384x384 f32) -> Bt (384x16640 bf16) transpose
// blocks [1536,1728): U1,U2 -> Bt tail columns
// blocks [1728,2240): neighbour_h -> h1bf, h2bf (m-major), h1t (i-major)
__global__ void prep_all(const float* __restrict__ A, const float* __restrict__ U1,
                         const float* __restrict__ U2, const float* __restrict__ nh,
                         ushort_t* __restrict__ Bt, ushort_t* __restrict__ h1,
                         ushort_t* __restrict__ h2, ushort_t* __restrict__ h1t) {
  __shared__ float sm[64][65];
  const int b = blockIdx.x;
  const int t = threadIdx.x;
  const int tx = t & 63, ty = t >> 6;
  if (b < 1536) {
    const int kt = b & 255, nt = b >> 8;
    const int k0 = kt * 64, n0 = nt * 64;
#pragma unroll
    for (int s = 0; s < 16; ++s) {
      int kk = ty + s * 4;
      sm[kk][tx] = A[(size_t)(k0 + kk) * NOUT + n0 + tx];
    }
    __syncthreads();
#pragma unroll
    for (int s = 0; s < 16; ++s) {
      int nn = ty + s * 4;
      Bt[(size_t)(n0 + nn) * BT_K + k0 + tx] = f2bf(sm[tx][nn]);
    }
  } else if (b < 1728) {
    int idx = (b - 1536) * 256 + t;   // 0..49151
    int n = idx >> 7, i = idx & 127;
    Bt[(size_t)n * BT_K + 16384 + i] = f2bf(U1[idx]);
    Bt[(size_t)n * BT_K + 16512 + i] = f2bf(U2[idx]);
  } else {
    const int g = b - 1728;           // 0..511
    const int mt = g & 255, jt = g >> 8;
    const int m0 = mt * 64, j0 = jt * 64;
#pragma unroll
    for (int s = 0; s < 16; ++s) {
      int mm = ty + s * 4;
      float f1 = nh[(size_t)(m0 + mm) * 256 + j0 + tx];
      float f2 = nh[(size_t)(m0 + mm) * 256 + 128 + j0 + tx];
      h1[(size_t)(m0 + mm) * HD + j0 + tx] = f2bf(f1);
      h2[(size_t)(m0 + mm) * HD + j0 + tx] = f2bf(f2);
      sm[mm][tx] = f1;
    }
    __syncthreads();
#pragma unroll
    for (int s = 0; s < 16; ++s) {
      int jj = ty + s * 4;
      h1t[(size_t)(j0 + jj) * N_NODES + m0 + tx] = f2bf(sm[tx][jj]);
    }
  }
}

// ---------------- main GEMM: out[m][n] = sum_k X[m,k] * Bt[n,k] (+bias) ----------------
// X[m, i*128+j] = h1[m,i]*h2[m,j] for i<128; X[m,16384+i]=h1[m,i]; X[m,16512+j]=h2[m,j]
// 130 K-tiles of 128: tile i<128 = outer-product slice i; 128=U1; 129=U2.
// All register arrays indexed by compile-time constants only (SROA-safe).
__global__ __launch_bounds__(256)
void gemm_kernel(const ushort_t* __restrict__ Bt, const ushort_t* __restrict__ h1bf,
                 const ushort_t* __restrict__ h2bf, const ushort_t* __restrict__ h1t,
                 const float* __restrict__ u2b, float* __restrict__ out) {
  __shared__ short bsh[128 * LSTR];   // B tile [n][k128], padded
  const int tid = threadIdx.x;
  const int bid = blockIdx.x;
  const int Nt = bid % 3, Mt = bid / 3;
  const int n0 = Nt * 128, m0 = Mt * 128;
  const int lane = tid & 63, wv = tid >> 6;
  const int l31 = lane & 31, oct = lane >> 5;
  const int wm = wv >> 1, wn = wv & 1;           // 2x2 wave grid
  const int mbase = m0 + wm * 64;
  const int nbase_l = wn * 64;

  // resident h2 A-fragments: rows mbase+ms*32+l31, k2 = c*16 + oct*8 + [0..8)
  uint4v h2u[2][8];
#pragma unroll
  for (int ms = 0; ms < 2; ++ms) {
    const ushort_t* hp = h2bf + (size_t)(mbase + ms * 32 + l31) * HD + oct * 8;
#pragma unroll
    for (int c = 0; c < 8; ++c)
      h2u[ms][c] = *reinterpret_cast<const uint4v*>(hp + c * 16);
  }

  f32x16 acc[2][2];
#pragma unroll
  for (int ms = 0; ms < 2; ++ms)
#pragma unroll
    for (int ns = 0; ns < 2; ++ns)
      acc[ms][ns] = (f32x16)(0.0f);

  // staging: 32 KB tile in two 16 KB halves through one breg[4] (16 VGPRs).
  // 16 consecutive tids cover one 256 B row: perfectly coalesced.
  const int prow = tid >> 4;          // 0..15
  const int poff = tid & 15;          // *16 B
  uint4 breg[4];
  auto load_half = [&](int it, int h) {
#pragma unroll
    for (int l = 0; l < 4; ++l) {
      int row = h * 64 + l * 16 + prow;
      breg[l] = *reinterpret_cast<const uint4*>(
          Bt + (size_t)(n0 + row) * BT_K + (size_t)it * 128 + poff * 8);
    }
  };
  auto write_half = [&](int h) {
#pragma unroll
    for (int l = 0; l < 4; ++l) {
      int row = h * 64 + l * 16 + prow;
      *reinterpret_cast<uint4*>(&bsh[row * LSTR + poff * 8]) = breg[l];
    }
  };

  load_half(0, 0);   // prologue: half0 of tile 0

  // h1 scalar rolling prefetch (one per ms-row)
  const int hrow0 = mbase + l31;
  const int hrow1 = mbase + 32 + l31;
  ushort_t hn0 = h1t[hrow0];
  ushort_t hn1 = h1t[hrow1];

  for (int it = 0; it < 130; ++it) {
    // invariant: breg holds half0(it) here (prev iter's reads of bsh done at its end barrier)
    write_half(0);
    load_half(it, 1);
    write_half(1);                    // ~300 cyc exposed L2 wait — accepted for 16-reg staging
    __syncthreads();
    if (it < 129) load_half(it + 1, 0);   // in flight across this tile's compute

    if (it < 128) {
      float h1f0 = __uint_as_float((uint_t)hn0 << 16);
      float h1f1 = __uint_as_float((uint_t)hn1 << 16);
      if (it < 127) {
        hn0 = h1t[(size_t)(it + 1) * N_NODES + hrow0];
        hn1 = h1t[(size_t)(it + 1) * N_NODES + hrow1];
      }
#pragma unroll
      for (int c = 0; c < 8; ++c) {
        bf16x8 b0 = *reinterpret_cast<const bf16x8*>(&bsh[(nbase_l + l31) * LSTR + c * 16 + oct * 8]);
        bf16x8 b1 = *reinterpret_cast<const bf16x8*>(&bsh[(nbase_l + 32 + l31) * LSTR + c * 16 + oct * 8]);
#pragma unroll
        for (int ms = 0; ms < 2; ++ms) {
          const float hf = ms ? h1f1 : h1f0;
          uint4v avu;
#pragma unroll
          for (int r = 0; r < 4; ++r) {
            uint_t u = h2u[ms][c][r];
            float lo = __uint_as_float(u << 16);
            float hi = __uint_as_float(u & 0xffff0000u);
            avu[r] = __builtin_amdgcn_perm(__float_as_uint(hi * hf), __float_as_uint(lo * hf),
                                           0x07060302u);
          }
          bf16x8 av = __builtin_bit_cast(bf16x8, avu);
          acc[ms][0] = __builtin_amdgcn_mfma_f32_32x32x16_bf16(av, b0, acc[ms][0], 0, 0, 0);
          acc[ms][1] = __builtin_amdgcn_mfma_f32_32x32x16_bf16(av, b1, acc[ms][1], 0, 0, 0);
        }
      }
    } else if (it == 128) {
      // A-fragment = h1 directly (linear U1 term)
#pragma unroll
      for (int c = 0; c < 8; ++c) {
        bf16x8 b0 = *reinterpret_cast<const bf16x8*>(&bsh[(nbase_l + l31) * LSTR + c * 16 + oct * 8]);
        bf16x8 b1 = *reinterpret_cast<const bf16x8*>(&bsh[(nbase_l + 32 + l31) * LSTR + c * 16 + oct * 8]);
#pragma unroll
        for (int ms = 0; ms < 2; ++ms) {
          bf16x8 a = *reinterpret_cast<const bf16x8*>(
              h1bf + (size_t)(mbase + ms * 32 + l31) * HD + c * 16 + oct * 8);
          acc[ms][0] = __builtin_amdgcn_mfma_f32_32x32x16_bf16(a, b0, acc[ms][0], 0, 0, 0);
          acc[ms][1] = __builtin_amdgcn_mfma_f32_32x32x16_bf16(a, b1, acc[ms][1], 0, 0, 0);
        }
      }
    } else {
      // A-fragment = h2 (linear U2 term), already resident
#pragma unroll
      for (int c = 0; c < 8; ++c) {
        bf16x8 b0 = *reinterpret_cast<const bf16x8*>(&bsh[(nbase_l + l31) * LSTR + c * 16 + oct * 8]);
        bf16x8 b1 = *reinterpret_cast<const bf16x8*>(&bsh[(nbase_l + 32 + l31) * LSTR + c * 16 + oct * 8]);
#pragma unroll
        for (int ms = 0; ms < 2; ++ms) {
          bf16x8 a = __builtin_bit_cast(bf16x8, h2u[ms][c]);
          acc[ms][0] = __builtin_amdgcn_mfma_f32_32x32x16_bf16(a, b0, acc[ms][0], 0, 0, 0);
          acc[ms][1] = __builtin_amdgcn_mfma_f32_32x32x16_bf16(a, b1, acc[ms][1], 0, 0, 0);
        }
      }
    }
    __syncthreads();
  }

  // epilogue: bias + store. C/D: col = lane&31, row = (reg&3) + 8*(reg>>2) + 4*oct
#pragma unroll
  for (int ns = 0; ns < 2; ++ns) {
    int col = n0 + nbase_l + ns * 32 + l31;
    float bias = u2b[col];
#pragma unroll
    for (int ms = 0; ms < 2; ++ms) {
#pragma unroll
      for (int r = 0; r < 16; ++r) {
        int row = (r & 3) + 8 * (r >> 2) + 4 * oct;
        int m = mbase + ms * 32 + row;
        out[(size_t)m * NOUT + col] = acc[ms][ns][r] + bias;
      }
    }
  }
}

extern "C" void kernel_launch(void* const* d_in, const int* in_sizes, int n_in,
                              void* d_out, int out_size, void* d_ws, size_t ws_size,
                              hipStream_t stream) {
  const float* nh  = (const float*)d_in[0];   // (16384, 2, 128)
  const float* A   = (const float*)d_in[1];   // (128, 128, 384)
  const float* U1  = (const float*)d_in[2];   // (384, 128)
  const float* U2  = (const float*)d_in[3];   // (384, 128)
  const float* U2b = (const float*)d_in[4];   // (384,)

  char* ws = (char*)d_ws;
  ushort_t* Bt   = (ushort_t*)(ws);                 // 384*16640*2  = 12,779,520
  ushort_t* h1bf = (ushort_t*)(ws + 12779520);      // 16384*128*2 =  4,194,304
  ushort_t* h2bf = (ushort_t*)(ws + 16973824);      //               4,194,304
  ushort_t* h1t  = (ushort_t*)(ws + 21168128);      //               4,194,304

  prep_all<<<dim3(2240), 256, 0, stream>>>(A, U1, U2, nh, Bt, h1bf, h2bf, h1t);
  gemm_kernel<<<dim3(384), 256, 0, stream>>>(Bt, h1bf, h2bf, h1t, U2b, (float*)d_out);
}